// Round 1
// baseline (3519.257 us; speedup 1.0000x reference)
//
#include <hip/hip_runtime.h>
#include <hip/hip_bf16.h>

#define N_NODES 100000
#define E_EDGES 1600000
#define NG 512
#define FIN 7
#define HID 128
#define NBUCK 782          // ceil(N_NODES/128), bucket = 128 consecutive dst nodes
#define NBLK_SC 256        // partition blocks (each owns a contiguous edge chunk)
#define CHUNK 6250         // E_EDGES / NBLK_SC (exact)
#define TLEN (NBUCK * NBLK_SC)   // 200192 table entries
#define NCH 196            // ceil(TLEN/1024) scan chunks
#define MMX_GRID 782       // ceil(N_NODES/128)
#define AGG_GRID 3125      // N_NODES / 32 (exact)

typedef __attribute__((ext_vector_type(8))) short bf16x8;
typedef __attribute__((ext_vector_type(4))) float f32x4;

// bf16 helpers: decode packed pair, encode with RNE
__device__ __forceinline__ float bf_lo(unsigned int u) { return __uint_as_float(u << 16); }
__device__ __forceinline__ float bf_hi(unsigned int u) { return __uint_as_float(u & 0xffff0000u); }
__device__ __forceinline__ unsigned int f2bf_rne(float f) {
    unsigned int x = __float_as_uint(f);
    return (x + 0x7fffu + ((x >> 16) & 1u)) >> 16;   // finite inputs only
}
__device__ __forceinline__ unsigned int pack_bf2(float lo, float hi) {
    return f2bf_rne(lo) | (f2bf_rne(hi) << 16);
}

// ------ CSR hist (0..255) + pooled zero (256..319) + Wc fold (320) + WT2/WT3 (321..448)

__global__ __launch_bounds__(256) void k_hist2(const int* __restrict__ eidx,
                                               int* __restrict__ table,
                                               const float* __restrict__ W4,
                                               const float* __restrict__ b4,
                                               const float* __restrict__ Wlin,
                                               const float* __restrict__ blin,
                                               float* __restrict__ Wc,
                                               float* __restrict__ bc,
                                               float* __restrict__ pooled,
                                               const float* __restrict__ W2,
                                               const float* __restrict__ W3,
                                               unsigned short* __restrict__ WT2,
                                               unsigned short* __restrict__ WT3) {
    __shared__ int h[NBUCK];
    int blk = blockIdx.x, t = threadIdx.x;
    if (blk >= NBLK_SC) {
        int r = blk - NBLK_SC;
        if (r < 64) {
            float4 z = {0.f, 0.f, 0.f, 0.f};
            *(float4*)&pooled[(r * 256 + t) * 4] = z;   // 64*256*16B = NG*HID*4
        } else if (r == 64) {
            int k = t >> 1, o = t & 1;
            float acc = 0.f;
            for (int j = 0; j < HID; ++j) acc += W4[k * HID + j] * Wlin[j * 2 + o];
            Wc[k * 2 + o] = acc;
            if (k == 0) {
                float b = blin[o];
                for (int j = 0; j < HID; ++j) b += b4[j] * Wlin[j * 2 + o];
                bc[o] = b;
            }
        } else if (r < 129) {   // WT2: transpose+convert, 64 blocks x 256 = 16384 elems
            int idx = (r - 65) * 256 + t;
            int k = idx >> 7, n = idx & 127;
            WT2[n * 128 + k] = (unsigned short)f2bf_rne(W2[idx]);
        } else {                // WT3
            int idx = (r - 129) * 256 + t;
            int k = idx >> 7, n = idx & 127;
            WT3[n * 128 + k] = (unsigned short)f2bf_rne(W3[idx]);
        }
        return;
    }
    for (int i = t; i < NBUCK; i += 256) h[i] = 0;
    __syncthreads();
    int e0 = blk * CHUNK, e1 = e0 + CHUNK;
    for (int e = e0 + t; e < e1; e += 256)
        atomicAdd(&h[eidx[E_EDGES + e] >> 7], 1);
    __syncthreads();
    for (int i = t; i < NBUCK; i += 256)
        table[i * NBLK_SC + blk] = h[i];
}

__global__ void k_blocksum(const int* __restrict__ table, int* __restrict__ partial) {
    __shared__ int s[256];
    int b = blockIdx.x, t = threadIdx.x;
    int base = b * 1024;
    int sum = 0;
    for (int i = t; i < 1024; i += 256) {
        int idx = base + i;
        sum += (idx < TLEN) ? table[idx] : 0;
    }
    s[t] = sum; __syncthreads();
    for (int st = 128; st > 0; st >>= 1) {
        if (t < st) s[t] += s[t + st];
        __syncthreads();
    }
    if (t == 0) partial[b] = s[0];
}

// parallel exclusive scan of the 196 chunk sums (one 256-thread block)
__global__ void k_scan_blk(int* __restrict__ partial, int* __restrict__ bucketBase,
                           int* __restrict__ rowptr) {
    __shared__ int s[256];
    int t = threadIdx.x;
    int v = (t < NCH) ? partial[t] : 0;
    s[t] = v; __syncthreads();
    for (int st = 1; st < 256; st <<= 1) {
        int a = (t >= st) ? s[t - st] : 0;
        __syncthreads();
        s[t] += a;
        __syncthreads();
    }
    if (t < NCH) partial[t] = s[t] - v;   // exclusive
    if (t == 0) { bucketBase[NBUCK] = E_EDGES; rowptr[N_NODES] = E_EDGES; }
}

__global__ void k_scan_final(int* __restrict__ table, const int* __restrict__ partial,
                             int* __restrict__ bucketBase) {
    __shared__ int s[1024];
    int b = blockIdx.x, t = threadIdx.x;
    int idx = b * 1024 + t;
    int v = (idx < TLEN) ? table[idx] : 0;
    s[t] = v; __syncthreads();
    for (int st = 1; st < 1024; st <<= 1) {
        int add = (t >= st) ? s[t - st] : 0;
        __syncthreads();
        s[t] += add;
        __syncthreads();
    }
    if (idx < TLEN) {
        int ex = partial[b] + s[t] - v;   // exclusive
        table[idx] = ex;
        if ((idx & (NBLK_SC - 1)) == 0) bucketBase[idx / NBLK_SC] = ex;
    }
}

__global__ __launch_bounds__(256) void k_scatter2(const int* __restrict__ eidx,
                                                  const int* __restrict__ table,
                                                  unsigned int* __restrict__ ebuf) {
    __shared__ int loff[NBUCK];
    int blk = blockIdx.x, t = threadIdx.x;
    for (int i = t; i < NBUCK; i += 256) loff[i] = table[i * NBLK_SC + blk];
    __syncthreads();
    int e0 = blk * CHUNK, e1 = e0 + CHUNK;
    for (int e = e0 + t; e < e1; e += 256) {
        int s = eidx[e];
        int d = eidx[E_EDGES + e];
        int p = atomicAdd(&loff[d >> 7], 1);
        ebuf[p] = ((unsigned int)(d & 127) << 17) | (unsigned int)s;
    }
}

// col[] now stores packed (dlocal7<<20)|src so the aggregation kernel gets the
// dst-local index without a search. src < 2^17, dlocal7 < 128.
__global__ __launch_bounds__(256) void k_bucket(const unsigned int* __restrict__ ebuf,
                                                const int* __restrict__ bucketBase,
                                                int* __restrict__ rowptr,
                                                float* __restrict__ dinv,
                                                int* __restrict__ col) {
    __shared__ int scnt[128], soff[128], scur[128];
    int b = blockIdx.x, t = threadIdx.x;
    int bbase = bucketBase[b], bend = bucketBase[b + 1];
    if (t < 128) { scnt[t] = 0; scur[t] = 0; }
    __syncthreads();
    for (int e = bbase + t; e < bend; e += 256) {
        unsigned int rec = ebuf[e];
        atomicAdd(&scnt[rec >> 17], 1);
    }
    __syncthreads();
    if (t < 128) soff[t] = scnt[t];
    __syncthreads();
    for (int st = 1; st < 128; st <<= 1) {
        int a = (t < 128 && t >= st) ? soff[t - st] : 0;
        __syncthreads();
        if (t < 128) soff[t] += a;
        __syncthreads();
    }
    if (t < 128) {
        int ex = soff[t] - scnt[t];
        int node = b * 128 + t;
        if (node < N_NODES) {
            rowptr[node] = bbase + ex;
            dinv[node] = rsqrtf((float)(scnt[t] + 1));   // +1 self-loop
        }
        soff[t] = ex;
    }
    __syncthreads();
    for (int e = bbase + t; e < bend; e += 256) {
        unsigned int rec = ebuf[e];
        int dl = rec >> 17;
        int s = rec & 0x1FFFF;
        int p = bbase + soff[dl] + atomicAdd(&scur[dl], 1);
        col[p] = (dl << 20) | s;
    }
}

// ---------------- fused layer 1: g1 = bf16(dinv * relu((A' x) W1 + b1)) ----------------
// NOTE: output is PRE-SCALED by dinv[node] so downstream aggregation needs no dinv[src].

__global__ __launch_bounds__(256) void k_l1(const float* __restrict__ x,
                                            const float* __restrict__ W1,
                                            const float* __restrict__ b1,
                                            const int* __restrict__ rowptr,
                                            const int* __restrict__ col,
                                            const float* __restrict__ dinv,
                                            unsigned int* __restrict__ g1) {
    __shared__ float axs[32][8];       // 32 nodes x 7 feats (+pad)
    __shared__ float w1s[FIN * HID];   // 3.5 KB
    __shared__ float b1s[HID];
    int t = threadIdx.x;
    for (int i = t; i < FIN * HID; i += 256) w1s[i] = W1[i];
    if (t < HID) b1s[t] = b1[t];

    int lane = t & 63, wave = t >> 6;
    int sub = lane >> 3, f = lane & 7;          // node-subgroup, lane role
    int node = blockIdx.x * 32 + wave * 8 + sub;
    bool valid = node < N_NODES;
    float di = valid ? dinv[node] : 0.f;
    float a = (valid && f < 7) ? di * x[node * FIN + f] : 0.f;
    int e0 = valid ? rowptr[node] : 0;
    int e1 = valid ? rowptr[node + 1] : 0;
    for (int base = e0; base < e1; base += 8) {
        int mm = e1 - base; if (mm > 8) mm = 8;
        int sc = (f < mm) ? (col[base + f] & 0x1FFFF) : 0;
        for (int j = 0; j < mm; ++j) {
            int s = __shfl(sc, sub * 8 + j);
            float v = (f < 7) ? x[s * FIN + f] : dinv[s];
            float ds = __shfl(v, sub * 8 + 7);
            if (f < 7) a += ds * v;
        }
    }
    axs[wave * 8 + sub][f] = (f < 7) ? di * a : 0.f;
    __syncthreads();

    int nl = t >> 3, fb = t & 7;
    int gnode = blockIdx.x * 32 + nl;
    if (gnode < N_NODES) {
        float av[FIN];
        #pragma unroll
        for (int k = 0; k < FIN; ++k) av[k] = axs[nl][k];
        float dsc = dinv[gnode];
        unsigned int outp[8];
        #pragma unroll
        for (int p = 0; p < 8; ++p) {
            int fo = fb * 16 + p * 2;
            float acc0 = b1s[fo], acc1 = b1s[fo + 1];
            #pragma unroll
            for (int k = 0; k < FIN; ++k) {
                acc0 += av[k] * w1s[k * HID + fo];
                acc1 += av[k] * w1s[k * HID + fo + 1];
            }
            outp[p] = pack_bf2(dsc * fmaxf(acc0, 0.f), dsc * fmaxf(acc1, 0.f));
        }
        *(uint4*)&g1[(size_t)gnode * 64 + fb * 8] = *(uint4*)&outp[0];
        *(uint4*)&g1[(size_t)gnode * 64 + fb * 8 + 4] = *(uint4*)&outp[4];
    }
}

// ---------------- edge-centric aggregation with LDS fp32 accumulators ----------------
// Input rows are pre-scaled: gs[i] = dinv[i]*h[i]. Output is the TRUE aggregate:
//   out_i = dinv_i * (gs_i + sum_{s in N(i)} gs_s)
// Block owns 32 consecutive dst nodes (16 KB LDS acc). Edges for those nodes are a
// contiguous CSR range; waves stream it in 64-wide windows, 16-deep gather batches,
// accumulating via ds_add_f32. dst-local index comes packed in col (bits 20..26).

__global__ __launch_bounds__(256) void k_aggE(const unsigned int* __restrict__ gIn,
                                              unsigned int* __restrict__ gOut,
                                              const int* __restrict__ rowptr,
                                              const int* __restrict__ colv,
                                              const float* __restrict__ dinv) {
    __shared__ float sacc[32 * 128];
    int t = threadIdx.x, lane = t & 63, wave = t >> 6;
    int n0 = blockIdx.x * 32;

    // init accumulators with self term (rows are pre-scaled, so self = gs[i])
    #pragma unroll
    for (int r = 0; r < 8; ++r) {
        int nl = wave * 8 + r;
        unsigned int u = gIn[(size_t)(n0 + nl) * 64 + lane];
        float2 v; v.x = bf_lo(u); v.y = bf_hi(u);
        *(float2*)&sacc[nl * 128 + 2 * lane] = v;
    }
    int estart = rowptr[n0];
    int eend = rowptr[n0 + 32];
    __syncthreads();

    int ll2 = 2 * lane;
    for (int base = estart + wave * 64; base < eend; base += 256) {
        int m = eend - base; if (m > 64) m = 64;
        unsigned int cv = 0;
        if (lane < m) cv = (unsigned int)colv[base + lane];
        for (int j0 = 0; j0 < m; j0 += 16) {
            unsigned int u[16]; int db[16];
            #pragma unroll
            for (int q = 0; q < 16; ++q) {
                if (j0 + q < m) {
                    unsigned int rr = (unsigned int)__builtin_amdgcn_readlane((int)cv, j0 + q);
                    db[q] = (int)((rr >> 20) & 31u) * 128;
                    u[q] = gIn[(size_t)(rr & 0x1FFFFu) * 64 + lane];
                }
            }
            #pragma unroll
            for (int q = 0; q < 16; ++q) {
                if (j0 + q < m) {
                    atomicAdd(&sacc[db[q] + ll2], __uint_as_float(u[q] << 16));
                    atomicAdd(&sacc[db[q] + ll2 + 1], __uint_as_float(u[q] & 0xffff0000u));
                }
            }
        }
    }
    __syncthreads();

    #pragma unroll
    for (int r = 0; r < 8; ++r) {
        int nl = wave * 8 + r;
        float2 v = *(const float2*)&sacc[nl * 128 + 2 * lane];
        float di = dinv[n0 + nl];
        gOut[(size_t)(n0 + nl) * 64 + lane] = pack_bf2(di * v.x, di * v.y);
    }
}

// ---------------- MFMA matmul (layers 2,3): g_out = bf16(dinv * relu(A @ WT^T + b)) ---
// WTg: pre-transposed bf16 weights [n][k] (n-major). Staged to LDS stride 136.
// Output pre-scaled by dinv[node] for the next aggregation pass.

__global__ __launch_bounds__(256) void k_mmx(const unsigned int* __restrict__ gIn,
                                             const unsigned short* __restrict__ WTg,
                                             const float* __restrict__ bias,
                                             const float* __restrict__ dinv,
                                             unsigned int* __restrict__ outg) {
    __shared__ unsigned short sbuf[128 * 136];   // WT (stride 136), reused as Cs (stride 132)
    int t = threadIdx.x;
    // coalesced copy: 16384 shorts, 8 per thread per iter (uint4)
    for (int i = t * 8; i < 128 * 128; i += 256 * 8) {
        int n = i >> 7, k = i & 127;
        uint4 val = *(const uint4*)(WTg + i);
        *(uint4*)(sbuf + n * 136 + k) = val;
    }

    int lane = t & 63, wave = t >> 6;
    int m = lane & 15, quad = lane >> 4;
    int nodeBase = blockIdx.x * 128 + wave * 32;
    const short* gs = (const short*)gIn;

    float bi[8];
    #pragma unroll
    for (int nt = 0; nt < 8; ++nt) bi[nt] = bias[nt * 16 + m];

    f32x4 acc[2][8];
    #pragma unroll
    for (int gi = 0; gi < 2; ++gi)
        #pragma unroll
        for (int nt = 0; nt < 8; ++nt)
            acc[gi][nt] = (f32x4){0.f, 0.f, 0.f, 0.f};

    __syncthreads();

    #pragma unroll
    for (int kc = 0; kc < 4; ++kc) {
        bf16x8 ah[2];
        #pragma unroll
        for (int gi = 0; gi < 2; ++gi) {
            int node = nodeBase + gi * 16 + m;
            bf16x8 h = {0, 0, 0, 0, 0, 0, 0, 0};
            if (node < N_NODES)
                h = *(const bf16x8*)(gs + (size_t)node * 128 + kc * 32 + quad * 8);
            ah[gi] = h;
        }
        #pragma unroll
        for (int nt = 0; nt < 8; ++nt) {
            bf16x8 b = *(const bf16x8*)(sbuf + (nt * 16 + m) * 136 + kc * 32 + quad * 8);
            #pragma unroll
            for (int gi = 0; gi < 2; ++gi)
                acc[gi][nt] = __builtin_amdgcn_mfma_f32_16x16x32_bf16(ah[gi], b, acc[gi][nt], 0, 0, 0);
        }
    }

    __syncthreads();
    #pragma unroll
    for (int gi = 0; gi < 2; ++gi)
        #pragma unroll
        for (int r = 0; r < 4; ++r) {
            int nl = wave * 32 + gi * 16 + quad * 4 + r;
            int node = blockIdx.x * 128 + nl;
            float di = (node < N_NODES) ? dinv[node] : 0.f;
            #pragma unroll
            for (int nt = 0; nt < 8; ++nt) {
                float vv = acc[gi][nt][r] + bi[nt];
                sbuf[nl * 132 + nt * 16 + m] = (unsigned short)f2bf_rne(di * fmaxf(vv, 0.f));
            }
        }
    __syncthreads();
    for (int i = t; i < 128 * 32; i += 256) {
        int nl = i >> 5, p = i & 31;
        int node = blockIdx.x * 128 + nl;
        if (node < N_NODES) {
            uint2 val = *(const uint2*)(sbuf + nl * 132 + p * 4);
            *(uint2*)&outg[(size_t)node * 64 + p * 2] = val;
        }
    }
}

// ---------------- pool stage 1: per-chunk partial sums (bf16 in, fp32 atomics) -------

__global__ __launch_bounds__(256) void k_poolsum(const unsigned int* __restrict__ aggB,
                                                 const int* __restrict__ batch,
                                                 float* __restrict__ pooled) {
    int wid = (blockIdx.x * blockDim.x + threadIdx.x) >> 6;   // wave id: 16 nodes each
    int lane = threadIdx.x & 63;
    int n0 = wid * 16;
    if (n0 >= N_NODES) return;
    int n1 = n0 + 16; if (n1 > N_NODES) n1 = N_NODES;
    int curg = batch[n0];
    float ax = 0.f, ay = 0.f;
    for (int n = n0; n < n1; ++n) {
        int g = batch[n];
        if (g != curg) {
            atomicAdd(&pooled[curg * HID + 2 * lane], ax);
            atomicAdd(&pooled[curg * HID + 2 * lane + 1], ay);
            ax = 0.f; ay = 0.f; curg = g;
        }
        unsigned int u = aggB[(size_t)n * 64 + lane];
        ax += bf_lo(u); ay += bf_hi(u);
    }
    atomicAdd(&pooled[curg * HID + 2 * lane], ax);
    atomicAdd(&pooled[curg * HID + 2 * lane + 1], ay);
}

// ---------------- head: mean + fused W4*Wlin linear ----------------

__global__ void k_head(const float* __restrict__ pooled, const int* __restrict__ batch,
                       const float* __restrict__ Wc, const float* __restrict__ bc,
                       const float* __restrict__ blin, float* __restrict__ out) {
    int wid = (blockIdx.x * blockDim.x + threadIdx.x) >> 6;
    int lane = threadIdx.x & 63;
    if (wid >= NG) return;
    int g = wid;
    int lo = 0, hi = N_NODES;
    while (lo < hi) { int mid = (lo + hi) >> 1; if (batch[mid] < g) lo = mid + 1; else hi = mid; }
    int start = lo;
    hi = N_NODES;
    while (lo < hi) { int mid = (lo + hi) >> 1; if (batch[mid] < g + 1) lo = mid + 1; else hi = mid; }
    int cnt = lo - start;
    float invc = (cnt > 0) ? 1.0f / (float)cnt : 0.f;
    float px = pooled[g * HID + 2 * lane] * invc;
    float py = pooled[g * HID + 2 * lane + 1] * invc;

    #pragma unroll
    for (int o = 0; o < 2; ++o) {
        float v = px * Wc[(2 * lane) * 2 + o] + py * Wc[(2 * lane + 1) * 2 + o];
        #pragma unroll
        for (int s = 32; s > 0; s >>= 1) v += __shfl_down(v, s);
        if (lane == 0) out[g * 2 + o] = (cnt > 0) ? (v + bc[o]) : blin[o];
    }
}

// ---------------- launcher ----------------

extern "C" void kernel_launch(void* const* d_in, const int* in_sizes, int n_in,
                              void* d_out, int out_size, void* d_ws, size_t ws_size,
                              hipStream_t stream) {
    const float* x    = (const float*)d_in[0];
    const int*   eidx = (const int*)d_in[1];
    const int*   batch= (const int*)d_in[2];
    const float* W1   = (const float*)d_in[3];
    const float* b1   = (const float*)d_in[4];
    const float* W2   = (const float*)d_in[5];
    const float* b2   = (const float*)d_in[6];
    const float* W3   = (const float*)d_in[7];
    const float* b3   = (const float*)d_in[8];
    const float* W4   = (const float*)d_in[9];
    const float* b4   = (const float*)d_in[10];
    const float* Wlin = (const float*)d_in[11];
    const float* blin = (const float*)d_in[12];
    float* out = (float*)d_out;

    // workspace carve-up (256B aligned)
    char* ws = (char*)d_ws;
    size_t off = 0;
    auto carve = [&](size_t bytes) { char* p = ws + off; off = (off + bytes + 255) & ~(size_t)255; return p; };
    int*   rowptr    = (int*)carve((size_t)(N_NODES + 1) * 4);
    float* dinv      = (float*)carve((size_t)N_NODES * 4);
    int*   col       = (int*)carve((size_t)E_EDGES * 4);
    unsigned int* ebuf = (unsigned int*)carve((size_t)E_EDGES * 4);
    int*   table     = (int*)carve((size_t)TLEN * 4);
    int*   partial   = (int*)carve((size_t)NCH * 4);
    int*   bucketBase= (int*)carve((size_t)(NBUCK + 1) * 4);
    unsigned int* gA = (unsigned int*)carve((size_t)N_NODES * 64 * 4);   // 25.6 MB bf16 buffer
    unsigned int* gB = (unsigned int*)carve((size_t)N_NODES * 64 * 4);   // 25.6 MB bf16 buffer
    float* pooled    = (float*)carve((size_t)NG * HID * 4);
    float* Wc        = (float*)carve((size_t)HID * 2 * 4);
    float* bc        = (float*)carve(2 * 4);
    unsigned short* WT2 = (unsigned short*)carve((size_t)HID * HID * 2);
    unsigned short* WT3 = (unsigned short*)carve((size_t)HID * HID * 2);
    (void)ws_size; (void)n_in; (void)in_sizes; (void)out_size;

    const int BLK = 256;
    int gridL1 = (N_NODES + 31) / 32;               // 3125
    int gridPS = ((N_NODES + 15) / 16 * 64 + BLK - 1) / BLK;
    int gridHead = (NG * 64 + BLK - 1) / BLK;

    // CSR hist + pooled zero + Wc fold + WT2/WT3 conversion (single fused dispatch)
    k_hist2<<<NBLK_SC + 193, BLK, 0, stream>>>(eidx, table, W4, b4, Wlin, blin,
                                               Wc, bc, pooled, W2, W3, WT2, WT3);
    k_blocksum<<<NCH, BLK, 0, stream>>>(table, partial);
    k_scan_blk<<<1, 256, 0, stream>>>(partial, bucketBase, rowptr);
    k_scan_final<<<NCH, 1024, 0, stream>>>(table, partial, bucketBase);
    k_scatter2<<<NBLK_SC, BLK, 0, stream>>>(eidx, table, ebuf);
    k_bucket<<<NBUCK, BLK, 0, stream>>>(ebuf, bucketBase, rowptr, dinv, col);

    // layer 1 (fused agg + matmul), output pre-scaled by dinv
    k_l1<<<gridL1, BLK, 0, stream>>>(x, W1, b1, rowptr, col, dinv, gA);

    // layer 2: a2 = A' g1 -> MFMA mm (pre-scaled out) -> g2
    k_aggE<<<AGG_GRID, BLK, 0, stream>>>(gA, gB, rowptr, col, dinv);
    k_mmx<<<MMX_GRID, BLK, 0, stream>>>(gB, WT2, b2, dinv, gA);
    // layer 3: a3 = A' g2 -> MFMA mm (pre-scaled out) -> g3
    k_aggE<<<AGG_GRID, BLK, 0, stream>>>(gA, gB, rowptr, col, dinv);
    k_mmx<<<MMX_GRID, BLK, 0, stream>>>(gB, WT3, b3, dinv, gA);
    // layer 4: aggregation only (W4 folded into head), true aggregate out
    k_aggE<<<AGG_GRID, BLK, 0, stream>>>(gA, gB, rowptr, col, dinv);

    // pool + head
    k_poolsum<<<gridPS, BLK, 0, stream>>>(gB, batch, pooled);
    k_head<<<gridHead, BLK, 0, stream>>>(pooled, batch, Wc, bc, blin, out);
}

// Round 2
// 433.143 us; speedup vs baseline: 8.1249x; 8.1249x over previous
//
#include <hip/hip_runtime.h>
#include <hip/hip_bf16.h>

#define N_NODES 100000
#define E_EDGES 1600000
#define NG 512
#define FIN 7
#define HID 128
#define NBUCK 782          // ceil(N_NODES/128), bucket = 128 consecutive dst nodes
#define NBLK_SC 256        // partition blocks (each owns a contiguous edge chunk)
#define CHUNK 6250         // E_EDGES / NBLK_SC (exact)
#define TLEN (NBUCK * NBLK_SC)   // 200192 table entries
#define NCH 196            // ceil(TLEN/1024) scan chunks
#define MMX_GRID 782       // ceil(N_NODES/128)
#define AGG4_GRID 6250     // N_NODES / 16 nodes per block (4 waves x 4 nodes)

typedef __attribute__((ext_vector_type(8))) short bf16x8;
typedef __attribute__((ext_vector_type(4))) float f32x4;

// bf16 helpers: decode packed pair, encode with RNE
__device__ __forceinline__ float bf_lo(unsigned int u) { return __uint_as_float(u << 16); }
__device__ __forceinline__ float bf_hi(unsigned int u) { return __uint_as_float(u & 0xffff0000u); }
__device__ __forceinline__ unsigned int f2bf_rne(float f) {
    unsigned int x = __float_as_uint(f);
    return (x + 0x7fffu + ((x >> 16) & 1u)) >> 16;   // finite inputs only
}
__device__ __forceinline__ unsigned int pack_bf2(float lo, float hi) {
    return f2bf_rne(lo) | (f2bf_rne(hi) << 16);
}

// ------ CSR hist (0..255) + pooled zero (256..319) + Wc fold (320) + WT2/WT3 (321..448)

__global__ __launch_bounds__(256) void k_hist2(const int* __restrict__ eidx,
                                               int* __restrict__ table,
                                               const float* __restrict__ W4,
                                               const float* __restrict__ b4,
                                               const float* __restrict__ Wlin,
                                               const float* __restrict__ blin,
                                               float* __restrict__ Wc,
                                               float* __restrict__ bc,
                                               float* __restrict__ pooled,
                                               const float* __restrict__ W2,
                                               const float* __restrict__ W3,
                                               unsigned short* __restrict__ WT2,
                                               unsigned short* __restrict__ WT3) {
    __shared__ int h[NBUCK];
    int blk = blockIdx.x, t = threadIdx.x;
    if (blk >= NBLK_SC) {
        int r = blk - NBLK_SC;
        if (r < 64) {
            float4 z = {0.f, 0.f, 0.f, 0.f};
            *(float4*)&pooled[(r * 256 + t) * 4] = z;   // 64*256*16B = NG*HID*4
        } else if (r == 64) {
            int k = t >> 1, o = t & 1;
            float acc = 0.f;
            for (int j = 0; j < HID; ++j) acc += W4[k * HID + j] * Wlin[j * 2 + o];
            Wc[k * 2 + o] = acc;
            if (k == 0) {
                float b = blin[o];
                for (int j = 0; j < HID; ++j) b += b4[j] * Wlin[j * 2 + o];
                bc[o] = b;
            }
        } else if (r < 129) {   // WT2: transpose+convert, 64 blocks x 256 = 16384 elems
            int idx = (r - 65) * 256 + t;
            int k = idx >> 7, n = idx & 127;
            WT2[n * 128 + k] = (unsigned short)f2bf_rne(W2[idx]);
        } else {                // WT3
            int idx = (r - 129) * 256 + t;
            int k = idx >> 7, n = idx & 127;
            WT3[n * 128 + k] = (unsigned short)f2bf_rne(W3[idx]);
        }
        return;
    }
    for (int i = t; i < NBUCK; i += 256) h[i] = 0;
    __syncthreads();
    int e0 = blk * CHUNK, e1 = e0 + CHUNK;
    for (int e = e0 + t; e < e1; e += 256)
        atomicAdd(&h[eidx[E_EDGES + e] >> 7], 1);
    __syncthreads();
    for (int i = t; i < NBUCK; i += 256)
        table[i * NBLK_SC + blk] = h[i];
}

__global__ void k_blocksum(const int* __restrict__ table, int* __restrict__ partial) {
    __shared__ int s[256];
    int b = blockIdx.x, t = threadIdx.x;
    int base = b * 1024;
    int sum = 0;
    for (int i = t; i < 1024; i += 256) {
        int idx = base + i;
        sum += (idx < TLEN) ? table[idx] : 0;
    }
    s[t] = sum; __syncthreads();
    for (int st = 128; st > 0; st >>= 1) {
        if (t < st) s[t] += s[t + st];
        __syncthreads();
    }
    if (t == 0) partial[b] = s[0];
}

// parallel exclusive scan of the 196 chunk sums (one 256-thread block)
__global__ void k_scan_blk(int* __restrict__ partial, int* __restrict__ bucketBase,
                           int* __restrict__ rowptr) {
    __shared__ int s[256];
    int t = threadIdx.x;
    int v = (t < NCH) ? partial[t] : 0;
    s[t] = v; __syncthreads();
    for (int st = 1; st < 256; st <<= 1) {
        int a = (t >= st) ? s[t - st] : 0;
        __syncthreads();
        s[t] += a;
        __syncthreads();
    }
    if (t < NCH) partial[t] = s[t] - v;   // exclusive
    if (t == 0) { bucketBase[NBUCK] = E_EDGES; rowptr[N_NODES] = E_EDGES; }
}

__global__ void k_scan_final(int* __restrict__ table, const int* __restrict__ partial,
                             int* __restrict__ bucketBase) {
    __shared__ int s[1024];
    int b = blockIdx.x, t = threadIdx.x;
    int idx = b * 1024 + t;
    int v = (idx < TLEN) ? table[idx] : 0;
    s[t] = v; __syncthreads();
    for (int st = 1; st < 1024; st <<= 1) {
        int add = (t >= st) ? s[t - st] : 0;
        __syncthreads();
        s[t] += add;
        __syncthreads();
    }
    if (idx < TLEN) {
        int ex = partial[b] + s[t] - v;   // exclusive
        table[idx] = ex;
        if ((idx & (NBLK_SC - 1)) == 0) bucketBase[idx / NBLK_SC] = ex;
    }
}

__global__ __launch_bounds__(256) void k_scatter2(const int* __restrict__ eidx,
                                                  const int* __restrict__ table,
                                                  unsigned int* __restrict__ ebuf) {
    __shared__ int loff[NBUCK];
    int blk = blockIdx.x, t = threadIdx.x;
    for (int i = t; i < NBUCK; i += 256) loff[i] = table[i * NBLK_SC + blk];
    __syncthreads();
    int e0 = blk * CHUNK, e1 = e0 + CHUNK;
    for (int e = e0 + t; e < e1; e += 256) {
        int s = eidx[e];
        int d = eidx[E_EDGES + e];
        int p = atomicAdd(&loff[d >> 7], 1);
        ebuf[p] = ((unsigned int)(d & 127) << 17) | (unsigned int)s;
    }
}

// col[] stores packed (dlocal7<<20)|src. src < 2^17, dlocal7 < 128. Consumers mask.
__global__ __launch_bounds__(256) void k_bucket(const unsigned int* __restrict__ ebuf,
                                                const int* __restrict__ bucketBase,
                                                int* __restrict__ rowptr,
                                                float* __restrict__ dinv,
                                                int* __restrict__ col) {
    __shared__ int scnt[128], soff[128], scur[128];
    int b = blockIdx.x, t = threadIdx.x;
    int bbase = bucketBase[b], bend = bucketBase[b + 1];
    if (t < 128) { scnt[t] = 0; scur[t] = 0; }
    __syncthreads();
    for (int e = bbase + t; e < bend; e += 256) {
        unsigned int rec = ebuf[e];
        atomicAdd(&scnt[rec >> 17], 1);
    }
    __syncthreads();
    if (t < 128) soff[t] = scnt[t];
    __syncthreads();
    for (int st = 1; st < 128; st <<= 1) {
        int a = (t < 128 && t >= st) ? soff[t - st] : 0;
        __syncthreads();
        if (t < 128) soff[t] += a;
        __syncthreads();
    }
    if (t < 128) {
        int ex = soff[t] - scnt[t];
        int node = b * 128 + t;
        if (node < N_NODES) {
            rowptr[node] = bbase + ex;
            dinv[node] = rsqrtf((float)(scnt[t] + 1));   // +1 self-loop
        }
        soff[t] = ex;
    }
    __syncthreads();
    for (int e = bbase + t; e < bend; e += 256) {
        unsigned int rec = ebuf[e];
        int dl = rec >> 17;
        int s = rec & 0x1FFFF;
        int p = bbase + soff[dl] + atomicAdd(&scur[dl], 1);
        col[p] = (dl << 20) | s;
    }
}

// ---------------- fused layer 1: g1 = bf16(dinv * relu((A' x) W1 + b1)) ----------------
// Output is PRE-SCALED by dinv[node] so downstream aggregation needs no dinv[src].

__global__ __launch_bounds__(256) void k_l1(const float* __restrict__ x,
                                            const float* __restrict__ W1,
                                            const float* __restrict__ b1,
                                            const int* __restrict__ rowptr,
                                            const int* __restrict__ col,
                                            const float* __restrict__ dinv,
                                            unsigned int* __restrict__ g1) {
    __shared__ float axs[32][8];       // 32 nodes x 7 feats (+pad)
    __shared__ float w1s[FIN * HID];   // 3.5 KB
    __shared__ float b1s[HID];
    int t = threadIdx.x;
    for (int i = t; i < FIN * HID; i += 256) w1s[i] = W1[i];
    if (t < HID) b1s[t] = b1[t];

    int lane = t & 63, wave = t >> 6;
    int sub = lane >> 3, f = lane & 7;          // node-subgroup, lane role
    int node = blockIdx.x * 32 + wave * 8 + sub;
    bool valid = node < N_NODES;
    float di = valid ? dinv[node] : 0.f;
    float a = (valid && f < 7) ? di * x[node * FIN + f] : 0.f;
    int e0 = valid ? rowptr[node] : 0;
    int e1 = valid ? rowptr[node + 1] : 0;
    for (int base = e0; base < e1; base += 8) {
        int mm = e1 - base; if (mm > 8) mm = 8;
        int sc = (f < mm) ? (col[base + f] & 0x1FFFF) : 0;
        for (int j = 0; j < mm; ++j) {
            int s = __shfl(sc, sub * 8 + j);
            float v = (f < 7) ? x[s * FIN + f] : dinv[s];
            float ds = __shfl(v, sub * 8 + 7);
            if (f < 7) a += ds * v;
        }
    }
    axs[wave * 8 + sub][f] = (f < 7) ? di * a : 0.f;
    __syncthreads();

    int nl = t >> 3, fb = t & 7;
    int gnode = blockIdx.x * 32 + nl;
    if (gnode < N_NODES) {
        float av[FIN];
        #pragma unroll
        for (int k = 0; k < FIN; ++k) av[k] = axs[nl][k];
        float dsc = dinv[gnode];
        unsigned int outp[8];
        #pragma unroll
        for (int p = 0; p < 8; ++p) {
            int fo = fb * 16 + p * 2;
            float acc0 = b1s[fo], acc1 = b1s[fo + 1];
            #pragma unroll
            for (int k = 0; k < FIN; ++k) {
                acc0 += av[k] * w1s[k * HID + fo];
                acc1 += av[k] * w1s[k * HID + fo + 1];
            }
            outp[p] = pack_bf2(dsc * fmaxf(acc0, 0.f), dsc * fmaxf(acc1, 0.f));
        }
        *(uint4*)&g1[(size_t)gnode * 64 + fb * 8] = *(uint4*)&outp[0];
        *(uint4*)&g1[(size_t)gnode * 64 + fb * 8 + 4] = *(uint4*)&outp[4];
    }
}

// ---------------- aggregation: 4 nodes/wave, 16 lanes/row, uint4 gathers ----------------
// Input rows pre-scaled: gs[i] = dinv[i]*h[i]. Output: out_i = dinv_i*(gs_i + sum gs_s).
// Register accumulation (no LDS). Quarter-wave (16 lanes) owns one node; each lane
// holds a 16B (8-feature) row segment. One global_load_dwordx4 gathers 4 edges' rows
// (one per quarter) -> 4x MLP, 1/4 VMEM instrs vs wave-per-node. 16-deep batches.

__global__ __launch_bounds__(256) void k_agg4(const unsigned int* __restrict__ gIn,
                                              unsigned int* __restrict__ gOut,
                                              const int* __restrict__ rowptr,
                                              const int* __restrict__ colv,
                                              const float* __restrict__ dinv) {
    int wid = (blockIdx.x * blockDim.x + threadIdx.x) >> 6;
    int lane = threadIdx.x & 63;
    int q = lane >> 4, r = lane & 15;
    int node = wid * 4 + q;                       // N_NODES = 4*25000 exact
    if (node >= N_NODES) return;

    const uint4* grow = (const uint4*)gIn;        // row = 16 uint4 per node
    float di = dinv[node];

    uint4 su = grow[(size_t)node * 16 + r];       // self term (pre-scaled)
    float a0 = bf_lo(su.x), a1 = bf_hi(su.x);
    float a2 = bf_lo(su.y), a3 = bf_hi(su.y);
    float a4 = bf_lo(su.z), a5 = bf_hi(su.z);
    float a6 = bf_lo(su.w), a7 = bf_hi(su.w);

    int e0 = rowptr[node];
    int e1 = rowptr[node + 1];
    for (int base = e0; base < e1; base += 16) {
        int m = e1 - base; if (m > 16) m = 16;    // quarter-uniform
        int cv = (r < m) ? colv[base + r] : 0;
        uint4 u[16];
        #pragma unroll
        for (int j = 0; j < 16; ++j) {
            if (j < m) {
                int s = __shfl(cv, q * 16 + j) & 0x1FFFF;
                u[j] = grow[(size_t)s * 16 + r];
            }
        }
        #pragma unroll
        for (int j = 0; j < 16; ++j) {
            if (j < m) {
                a0 += bf_lo(u[j].x); a1 += bf_hi(u[j].x);
                a2 += bf_lo(u[j].y); a3 += bf_hi(u[j].y);
                a4 += bf_lo(u[j].z); a5 += bf_hi(u[j].z);
                a6 += bf_lo(u[j].w); a7 += bf_hi(u[j].w);
            }
        }
    }

    uint4 o;
    o.x = pack_bf2(di * a0, di * a1);
    o.y = pack_bf2(di * a2, di * a3);
    o.z = pack_bf2(di * a4, di * a5);
    o.w = pack_bf2(di * a6, di * a7);
    *(uint4*)&gOut[(size_t)node * 64 + r * 4] = o;
}

// ---------------- MFMA matmul (layers 2,3): g_out = bf16(dinv * relu(A @ WT^T + b)) ---
// WTg: pre-transposed bf16 weights [n][k] (n-major). Staged to LDS stride 136.
// Output pre-scaled by dinv[node] for the next aggregation pass.

__global__ __launch_bounds__(256) void k_mmx(const unsigned int* __restrict__ gIn,
                                             const unsigned short* __restrict__ WTg,
                                             const float* __restrict__ bias,
                                             const float* __restrict__ dinv,
                                             unsigned int* __restrict__ outg) {
    __shared__ unsigned short sbuf[128 * 136];   // WT (stride 136), reused as Cs (stride 132)
    int t = threadIdx.x;
    // coalesced copy: 16384 shorts, 8 per thread per iter (uint4)
    for (int i = t * 8; i < 128 * 128; i += 256 * 8) {
        int n = i >> 7, k = i & 127;
        uint4 val = *(const uint4*)(WTg + i);
        *(uint4*)(sbuf + n * 136 + k) = val;
    }

    int lane = t & 63, wave = t >> 6;
    int m = lane & 15, quad = lane >> 4;
    int nodeBase = blockIdx.x * 128 + wave * 32;
    const short* gs = (const short*)gIn;

    float bi[8];
    #pragma unroll
    for (int nt = 0; nt < 8; ++nt) bi[nt] = bias[nt * 16 + m];

    f32x4 acc[2][8];
    #pragma unroll
    for (int gi = 0; gi < 2; ++gi)
        #pragma unroll
        for (int nt = 0; nt < 8; ++nt)
            acc[gi][nt] = (f32x4){0.f, 0.f, 0.f, 0.f};

    __syncthreads();

    #pragma unroll
    for (int kc = 0; kc < 4; ++kc) {
        bf16x8 ah[2];
        #pragma unroll
        for (int gi = 0; gi < 2; ++gi) {
            int node = nodeBase + gi * 16 + m;
            bf16x8 h = {0, 0, 0, 0, 0, 0, 0, 0};
            if (node < N_NODES)
                h = *(const bf16x8*)(gs + (size_t)node * 128 + kc * 32 + quad * 8);
            ah[gi] = h;
        }
        #pragma unroll
        for (int nt = 0; nt < 8; ++nt) {
            bf16x8 b = *(const bf16x8*)(sbuf + (nt * 16 + m) * 136 + kc * 32 + quad * 8);
            #pragma unroll
            for (int gi = 0; gi < 2; ++gi)
                acc[gi][nt] = __builtin_amdgcn_mfma_f32_16x16x32_bf16(ah[gi], b, acc[gi][nt], 0, 0, 0);
        }
    }

    __syncthreads();
    #pragma unroll
    for (int gi = 0; gi < 2; ++gi)
        #pragma unroll
        for (int r = 0; r < 4; ++r) {
            int nl = wave * 32 + gi * 16 + quad * 4 + r;
            int node = blockIdx.x * 128 + nl;
            float di = (node < N_NODES) ? dinv[node] : 0.f;
            #pragma unroll
            for (int nt = 0; nt < 8; ++nt) {
                float vv = acc[gi][nt][r] + bi[nt];
                sbuf[nl * 132 + nt * 16 + m] = (unsigned short)f2bf_rne(di * fmaxf(vv, 0.f));
            }
        }
    __syncthreads();
    for (int i = t; i < 128 * 32; i += 256) {
        int nl = i >> 5, p = i & 31;
        int node = blockIdx.x * 128 + nl;
        if (node < N_NODES) {
            uint2 val = *(const uint2*)(sbuf + nl * 132 + p * 4);
            *(uint2*)&outg[(size_t)node * 64 + p * 2] = val;
        }
    }
}

// ---------------- pool stage 1: per-chunk partial sums (bf16 in, fp32 atomics) -------

__global__ __launch_bounds__(256) void k_poolsum(const unsigned int* __restrict__ aggB,
                                                 const int* __restrict__ batch,
                                                 float* __restrict__ pooled) {
    int wid = (blockIdx.x * blockDim.x + threadIdx.x) >> 6;   // wave id: 16 nodes each
    int lane = threadIdx.x & 63;
    int n0 = wid * 16;
    if (n0 >= N_NODES) return;
    int n1 = n0 + 16; if (n1 > N_NODES) n1 = N_NODES;
    int curg = batch[n0];
    float ax = 0.f, ay = 0.f;
    for (int n = n0; n < n1; ++n) {
        int g = batch[n];
        if (g != curg) {
            atomicAdd(&pooled[curg * HID + 2 * lane], ax);
            atomicAdd(&pooled[curg * HID + 2 * lane + 1], ay);
            ax = 0.f; ay = 0.f; curg = g;
        }
        unsigned int u = aggB[(size_t)n * 64 + lane];
        ax += bf_lo(u); ay += bf_hi(u);
    }
    atomicAdd(&pooled[curg * HID + 2 * lane], ax);
    atomicAdd(&pooled[curg * HID + 2 * lane + 1], ay);
}

// ---------------- head: mean + fused W4*Wlin linear ----------------

__global__ void k_head(const float* __restrict__ pooled, const int* __restrict__ batch,
                       const float* __restrict__ Wc, const float* __restrict__ bc,
                       const float* __restrict__ blin, float* __restrict__ out) {
    int wid = (blockIdx.x * blockDim.x + threadIdx.x) >> 6;
    int lane = threadIdx.x & 63;
    if (wid >= NG) return;
    int g = wid;
    int lo = 0, hi = N_NODES;
    while (lo < hi) { int mid = (lo + hi) >> 1; if (batch[mid] < g) lo = mid + 1; else hi = mid; }
    int start = lo;
    hi = N_NODES;
    while (lo < hi) { int mid = (lo + hi) >> 1; if (batch[mid] < g + 1) lo = mid + 1; else hi = mid; }
    int cnt = lo - start;
    float invc = (cnt > 0) ? 1.0f / (float)cnt : 0.f;
    float px = pooled[g * HID + 2 * lane] * invc;
    float py = pooled[g * HID + 2 * lane + 1] * invc;

    #pragma unroll
    for (int o = 0; o < 2; ++o) {
        float v = px * Wc[(2 * lane) * 2 + o] + py * Wc[(2 * lane + 1) * 2 + o];
        #pragma unroll
        for (int s = 32; s > 0; s >>= 1) v += __shfl_down(v, s);
        if (lane == 0) out[g * 2 + o] = (cnt > 0) ? (v + bc[o]) : blin[o];
    }
}

// ---------------- launcher ----------------

extern "C" void kernel_launch(void* const* d_in, const int* in_sizes, int n_in,
                              void* d_out, int out_size, void* d_ws, size_t ws_size,
                              hipStream_t stream) {
    const float* x    = (const float*)d_in[0];
    const int*   eidx = (const int*)d_in[1];
    const int*   batch= (const int*)d_in[2];
    const float* W1   = (const float*)d_in[3];
    const float* b1   = (const float*)d_in[4];
    const float* W2   = (const float*)d_in[5];
    const float* b2   = (const float*)d_in[6];
    const float* W3   = (const float*)d_in[7];
    const float* b3   = (const float*)d_in[8];
    const float* W4   = (const float*)d_in[9];
    const float* b4   = (const float*)d_in[10];
    const float* Wlin = (const float*)d_in[11];
    const float* blin = (const float*)d_in[12];
    float* out = (float*)d_out;

    // workspace carve-up (256B aligned)
    char* ws = (char*)d_ws;
    size_t off = 0;
    auto carve = [&](size_t bytes) { char* p = ws + off; off = (off + bytes + 255) & ~(size_t)255; return p; };
    int*   rowptr    = (int*)carve((size_t)(N_NODES + 1) * 4);
    float* dinv      = (float*)carve((size_t)N_NODES * 4);
    int*   col       = (int*)carve((size_t)E_EDGES * 4);
    unsigned int* ebuf = (unsigned int*)carve((size_t)E_EDGES * 4);
    int*   table     = (int*)carve((size_t)TLEN * 4);
    int*   partial   = (int*)carve((size_t)NCH * 4);
    int*   bucketBase= (int*)carve((size_t)(NBUCK + 1) * 4);
    unsigned int* gA = (unsigned int*)carve((size_t)N_NODES * 64 * 4);   // 25.6 MB bf16 buffer
    unsigned int* gB = (unsigned int*)carve((size_t)N_NODES * 64 * 4);   // 25.6 MB bf16 buffer
    float* pooled    = (float*)carve((size_t)NG * HID * 4);
    float* Wc        = (float*)carve((size_t)HID * 2 * 4);
    float* bc        = (float*)carve(2 * 4);
    unsigned short* WT2 = (unsigned short*)carve((size_t)HID * HID * 2);
    unsigned short* WT3 = (unsigned short*)carve((size_t)HID * HID * 2);
    (void)ws_size; (void)n_in; (void)in_sizes; (void)out_size;

    const int BLK = 256;
    int gridL1 = (N_NODES + 31) / 32;               // 3125
    int gridPS = ((N_NODES + 15) / 16 * 64 + BLK - 1) / BLK;
    int gridHead = (NG * 64 + BLK - 1) / BLK;

    // CSR hist + pooled zero + Wc fold + WT2/WT3 conversion (single fused dispatch)
    k_hist2<<<NBLK_SC + 193, BLK, 0, stream>>>(eidx, table, W4, b4, Wlin, blin,
                                               Wc, bc, pooled, W2, W3, WT2, WT3);
    k_blocksum<<<NCH, BLK, 0, stream>>>(table, partial);
    k_scan_blk<<<1, 256, 0, stream>>>(partial, bucketBase, rowptr);
    k_scan_final<<<NCH, 1024, 0, stream>>>(table, partial, bucketBase);
    k_scatter2<<<NBLK_SC, BLK, 0, stream>>>(eidx, table, ebuf);
    k_bucket<<<NBUCK, BLK, 0, stream>>>(ebuf, bucketBase, rowptr, dinv, col);

    // layer 1 (fused agg + matmul), output pre-scaled by dinv
    k_l1<<<gridL1, BLK, 0, stream>>>(x, W1, b1, rowptr, col, dinv, gA);

    // layer 2: a2 = A' g1 -> MFMA mm (pre-scaled out) -> g2
    k_agg4<<<AGG4_GRID, BLK, 0, stream>>>(gA, gB, rowptr, col, dinv);
    k_mmx<<<MMX_GRID, BLK, 0, stream>>>(gB, WT2, b2, dinv, gA);
    // layer 3: a3 = A' g2 -> MFMA mm (pre-scaled out) -> g3
    k_agg4<<<AGG4_GRID, BLK, 0, stream>>>(gA, gB, rowptr, col, dinv);
    k_mmx<<<MMX_GRID, BLK, 0, stream>>>(gB, WT3, b3, dinv, gA);
    // layer 4: aggregation only (W4 folded into head), true aggregate out
    k_agg4<<<AGG4_GRID, BLK, 0, stream>>>(gA, gB, rowptr, col, dinv);

    // pool + head
    k_poolsum<<<gridPS, BLK, 0, stream>>>(gB, batch, pooled);
    k_head<<<gridHead, BLK, 0, stream>>>(pooled, batch, Wc, bc, blin, out);
}

// Round 3
// 407.767 us; speedup vs baseline: 8.6306x; 1.0622x over previous
//
#include <hip/hip_runtime.h>
#include <hip/hip_bf16.h>

#define N_NODES 100000
#define E_EDGES 1600000
#define NG 512
#define FIN 7
#define HID 128
#define NBUCK 782          // ceil(N_NODES/128), bucket = 128 consecutive dst nodes
#define NBLK_SC 256        // partition blocks (each owns a contiguous edge chunk)
#define CHUNK 6250         // E_EDGES / NBLK_SC (exact)
#define TLEN (NBUCK * NBLK_SC)   // 200192 table entries
#define NCH 196            // ceil(TLEN/1024) scan chunks
#define MMX_GRID 782       // ceil(N_NODES/128)
#define AGGW_GRID 25000    // N_NODES waves, 4 waves per block

typedef __attribute__((ext_vector_type(8))) short bf16x8;
typedef __attribute__((ext_vector_type(4))) float f32x4;

// bf16 helpers: decode packed pair, encode with RNE
__device__ __forceinline__ float bf_lo(unsigned int u) { return __uint_as_float(u << 16); }
__device__ __forceinline__ float bf_hi(unsigned int u) { return __uint_as_float(u & 0xffff0000u); }
__device__ __forceinline__ unsigned int f2bf_rne(float f) {
    unsigned int x = __float_as_uint(f);
    return (x + 0x7fffu + ((x >> 16) & 1u)) >> 16;   // finite inputs only
}
__device__ __forceinline__ unsigned int pack_bf2(float lo, float hi) {
    return f2bf_rne(lo) | (f2bf_rne(hi) << 16);
}

// ------ CSR hist (0..255) + pooled zero (256..319) + Wc fold (320) + WT2/WT3 (321..448)

__global__ __launch_bounds__(256) void k_hist2(const int* __restrict__ eidx,
                                               int* __restrict__ table,
                                               const float* __restrict__ W4,
                                               const float* __restrict__ b4,
                                               const float* __restrict__ Wlin,
                                               const float* __restrict__ blin,
                                               float* __restrict__ Wc,
                                               float* __restrict__ bc,
                                               float* __restrict__ pooled,
                                               const float* __restrict__ W2,
                                               const float* __restrict__ W3,
                                               unsigned short* __restrict__ WT2,
                                               unsigned short* __restrict__ WT3) {
    __shared__ int h[NBUCK];
    int blk = blockIdx.x, t = threadIdx.x;
    if (blk >= NBLK_SC) {
        int r = blk - NBLK_SC;
        if (r < 64) {
            float4 z = {0.f, 0.f, 0.f, 0.f};
            *(float4*)&pooled[(r * 256 + t) * 4] = z;   // 64*256*16B = NG*HID*4
        } else if (r == 64) {
            int k = t >> 1, o = t & 1;
            float acc = 0.f;
            for (int j = 0; j < HID; ++j) acc += W4[k * HID + j] * Wlin[j * 2 + o];
            Wc[k * 2 + o] = acc;
            if (k == 0) {
                float b = blin[o];
                for (int j = 0; j < HID; ++j) b += b4[j] * Wlin[j * 2 + o];
                bc[o] = b;
            }
        } else if (r < 129) {   // WT2: transpose+convert, 64 blocks x 256 = 16384 elems
            int idx = (r - 65) * 256 + t;
            int k = idx >> 7, n = idx & 127;
            WT2[n * 128 + k] = (unsigned short)f2bf_rne(W2[idx]);
        } else {                // WT3
            int idx = (r - 129) * 256 + t;
            int k = idx >> 7, n = idx & 127;
            WT3[n * 128 + k] = (unsigned short)f2bf_rne(W3[idx]);
        }
        return;
    }
    for (int i = t; i < NBUCK; i += 256) h[i] = 0;
    __syncthreads();
    int e0 = blk * CHUNK, e1 = e0 + CHUNK;
    for (int e = e0 + t; e < e1; e += 256)
        atomicAdd(&h[eidx[E_EDGES + e] >> 7], 1);
    __syncthreads();
    for (int i = t; i < NBUCK; i += 256)
        table[i * NBLK_SC + blk] = h[i];
}

__global__ void k_blocksum(const int* __restrict__ table, int* __restrict__ partial) {
    __shared__ int s[256];
    int b = blockIdx.x, t = threadIdx.x;
    int base = b * 1024;
    int sum = 0;
    for (int i = t; i < 1024; i += 256) {
        int idx = base + i;
        sum += (idx < TLEN) ? table[idx] : 0;
    }
    s[t] = sum; __syncthreads();
    for (int st = 128; st > 0; st >>= 1) {
        if (t < st) s[t] += s[t + st];
        __syncthreads();
    }
    if (t == 0) partial[b] = s[0];
}

// parallel exclusive scan of the 196 chunk sums (one 256-thread block)
__global__ void k_scan_blk(int* __restrict__ partial, int* __restrict__ bucketBase,
                           int* __restrict__ rowptr) {
    __shared__ int s[256];
    int t = threadIdx.x;
    int v = (t < NCH) ? partial[t] : 0;
    s[t] = v; __syncthreads();
    for (int st = 1; st < 256; st <<= 1) {
        int a = (t >= st) ? s[t - st] : 0;
        __syncthreads();
        s[t] += a;
        __syncthreads();
    }
    if (t < NCH) partial[t] = s[t] - v;   // exclusive
    if (t == 0) { bucketBase[NBUCK] = E_EDGES; rowptr[N_NODES] = E_EDGES; }
}

__global__ void k_scan_final(int* __restrict__ table, const int* __restrict__ partial,
                             int* __restrict__ bucketBase) {
    __shared__ int s[1024];
    int b = blockIdx.x, t = threadIdx.x;
    int idx = b * 1024 + t;
    int v = (idx < TLEN) ? table[idx] : 0;
    s[t] = v; __syncthreads();
    for (int st = 1; st < 1024; st <<= 1) {
        int add = (t >= st) ? s[t - st] : 0;
        __syncthreads();
        s[t] += add;
        __syncthreads();
    }
    if (idx < TLEN) {
        int ex = partial[b] + s[t] - v;   // exclusive
        table[idx] = ex;
        if ((idx & (NBLK_SC - 1)) == 0) bucketBase[idx / NBLK_SC] = ex;
    }
}

__global__ __launch_bounds__(256) void k_scatter2(const int* __restrict__ eidx,
                                                  const int* __restrict__ table,
                                                  unsigned int* __restrict__ ebuf) {
    __shared__ int loff[NBUCK];
    int blk = blockIdx.x, t = threadIdx.x;
    for (int i = t; i < NBUCK; i += 256) loff[i] = table[i * NBLK_SC + blk];
    __syncthreads();
    int e0 = blk * CHUNK, e1 = e0 + CHUNK;
    for (int e = e0 + t; e < e1; e += 256) {
        int s = eidx[e];
        int d = eidx[E_EDGES + e];
        int p = atomicAdd(&loff[d >> 7], 1);
        ebuf[p] = ((unsigned int)(d & 127) << 17) | (unsigned int)s;
    }
}

// col[] stores plain src node id (no packing — nothing downstream needs dlocal).
__global__ __launch_bounds__(256) void k_bucket(const unsigned int* __restrict__ ebuf,
                                                const int* __restrict__ bucketBase,
                                                int* __restrict__ rowptr,
                                                float* __restrict__ dinv,
                                                int* __restrict__ col) {
    __shared__ int scnt[128], soff[128], scur[128];
    int b = blockIdx.x, t = threadIdx.x;
    int bbase = bucketBase[b], bend = bucketBase[b + 1];
    if (t < 128) { scnt[t] = 0; scur[t] = 0; }
    __syncthreads();
    for (int e = bbase + t; e < bend; e += 256) {
        unsigned int rec = ebuf[e];
        atomicAdd(&scnt[rec >> 17], 1);
    }
    __syncthreads();
    if (t < 128) soff[t] = scnt[t];
    __syncthreads();
    for (int st = 1; st < 128; st <<= 1) {
        int a = (t < 128 && t >= st) ? soff[t - st] : 0;
        __syncthreads();
        if (t < 128) soff[t] += a;
        __syncthreads();
    }
    if (t < 128) {
        int ex = soff[t] - scnt[t];
        int node = b * 128 + t;
        if (node < N_NODES) {
            rowptr[node] = bbase + ex;
            dinv[node] = rsqrtf((float)(scnt[t] + 1));   // +1 self-loop
        }
        soff[t] = ex;
    }
    __syncthreads();
    for (int e = bbase + t; e < bend; e += 256) {
        unsigned int rec = ebuf[e];
        int dl = rec >> 17;
        int s = rec & 0x1FFFF;
        int p = bbase + soff[dl] + atomicAdd(&scur[dl], 1);
        col[p] = s;
    }
}

// ---------------- fused layer 1: g1 = bf16(dinv * relu((A' x) W1 + b1)) ----------------
// Output is PRE-SCALED by dinv[node] so downstream aggregation needs no dinv[src].

__global__ __launch_bounds__(256) void k_l1(const float* __restrict__ x,
                                            const float* __restrict__ W1,
                                            const float* __restrict__ b1,
                                            const int* __restrict__ rowptr,
                                            const int* __restrict__ col,
                                            const float* __restrict__ dinv,
                                            unsigned int* __restrict__ g1) {
    __shared__ float axs[32][8];       // 32 nodes x 7 feats (+pad)
    __shared__ float w1s[FIN * HID];   // 3.5 KB
    __shared__ float b1s[HID];
    int t = threadIdx.x;
    for (int i = t; i < FIN * HID; i += 256) w1s[i] = W1[i];
    if (t < HID) b1s[t] = b1[t];

    int lane = t & 63, wave = t >> 6;
    int sub = lane >> 3, f = lane & 7;          // node-subgroup, lane role
    int node = blockIdx.x * 32 + wave * 8 + sub;
    bool valid = node < N_NODES;
    float di = valid ? dinv[node] : 0.f;
    float a = (valid && f < 7) ? di * x[node * FIN + f] : 0.f;
    int e0 = valid ? rowptr[node] : 0;
    int e1 = valid ? rowptr[node + 1] : 0;
    for (int base = e0; base < e1; base += 8) {
        int mm = e1 - base; if (mm > 8) mm = 8;
        int sc = (f < mm) ? col[base + f] : 0;
        for (int j = 0; j < mm; ++j) {
            int s = __shfl(sc, sub * 8 + j);
            float v = (f < 7) ? x[s * FIN + f] : dinv[s];
            float ds = __shfl(v, sub * 8 + 7);
            if (f < 7) a += ds * v;
        }
    }
    axs[wave * 8 + sub][f] = (f < 7) ? di * a : 0.f;
    __syncthreads();

    int nl = t >> 3, fb = t & 7;
    int gnode = blockIdx.x * 32 + nl;
    if (gnode < N_NODES) {
        float av[FIN];
        #pragma unroll
        for (int k = 0; k < FIN; ++k) av[k] = axs[nl][k];
        float dsc = dinv[gnode];
        unsigned int outp[8];
        #pragma unroll
        for (int p = 0; p < 8; ++p) {
            int fo = fb * 16 + p * 2;
            float acc0 = b1s[fo], acc1 = b1s[fo + 1];
            #pragma unroll
            for (int k = 0; k < FIN; ++k) {
                acc0 += av[k] * w1s[k * HID + fo];
                acc1 += av[k] * w1s[k * HID + fo + 1];
            }
            outp[p] = pack_bf2(dsc * fmaxf(acc0, 0.f), dsc * fmaxf(acc1, 0.f));
        }
        *(uint4*)&g1[(size_t)gnode * 64 + fb * 8] = *(uint4*)&outp[0];
        *(uint4*)&g1[(size_t)gnode * 64 + fb * 8 + 4] = *(uint4*)&outp[4];
    }
}

// ---------------- aggregation: wave/node, pre-scaled rows, prefetched windows --------
// Input rows pre-scaled: gs[i] = dinv[i]*h[i]. Output: out_i = dinv_i*(gs_i + sum gs_s).
// R0 structure (uniform per-wave control flow, unconditional 8-deep batches) minus the
// per-edge dinv gather & dsv shfls (pre-scaling), plus: unconditional cv window load
// (safe over-read, ebuf follows col in workspace) and cross-window cv prefetch.

__global__ __launch_bounds__(256) void k_aggW(const unsigned int* __restrict__ gIn,
                                              unsigned int* __restrict__ gOut,
                                              const int* __restrict__ rowptr,
                                              const int* __restrict__ colv,
                                              const float* __restrict__ dinv) {
    int wid = (blockIdx.x * blockDim.x + threadIdx.x) >> 6;
    int lane = threadIdx.x & 63;
    if (wid >= N_NODES) return;
    int i = wid;
    float di = dinv[i];
    int e0 = rowptr[i], e1 = rowptr[i + 1];
    int cv = colv[e0 + lane];                     // over-read past e1 is safe/unused
    unsigned int v = gIn[(size_t)i * 64 + lane];  // self term (pre-scaled)
    float ax = bf_lo(v), ay = bf_hi(v);

    for (int base = e0; base < e1; base += 64) {
        int m = e1 - base; if (m > 64) m = 64;
        int cvn = cv;
        if (base + 64 < e1) cvn = colv[base + 64 + lane];   // prefetch next window
        int j = 0;
        for (; j + 7 < m; j += 8) {
            int s0 = __shfl(cv, j),     s1 = __shfl(cv, j + 1);
            int s2 = __shfl(cv, j + 2), s3 = __shfl(cv, j + 3);
            int s4 = __shfl(cv, j + 4), s5 = __shfl(cv, j + 5);
            int s6 = __shfl(cv, j + 6), s7 = __shfl(cv, j + 7);
            unsigned int u0 = gIn[(size_t)s0 * 64 + lane];
            unsigned int u1 = gIn[(size_t)s1 * 64 + lane];
            unsigned int u2 = gIn[(size_t)s2 * 64 + lane];
            unsigned int u3 = gIn[(size_t)s3 * 64 + lane];
            unsigned int u4 = gIn[(size_t)s4 * 64 + lane];
            unsigned int u5 = gIn[(size_t)s5 * 64 + lane];
            unsigned int u6 = gIn[(size_t)s6 * 64 + lane];
            unsigned int u7 = gIn[(size_t)s7 * 64 + lane];
            ax += bf_lo(u0); ay += bf_hi(u0);
            ax += bf_lo(u1); ay += bf_hi(u1);
            ax += bf_lo(u2); ay += bf_hi(u2);
            ax += bf_lo(u3); ay += bf_hi(u3);
            ax += bf_lo(u4); ay += bf_hi(u4);
            ax += bf_lo(u5); ay += bf_hi(u5);
            ax += bf_lo(u6); ay += bf_hi(u6);
            ax += bf_lo(u7); ay += bf_hi(u7);
        }
        for (; j + 3 < m; j += 4) {
            int s0 = __shfl(cv, j),     s1 = __shfl(cv, j + 1);
            int s2 = __shfl(cv, j + 2), s3 = __shfl(cv, j + 3);
            unsigned int u0 = gIn[(size_t)s0 * 64 + lane];
            unsigned int u1 = gIn[(size_t)s1 * 64 + lane];
            unsigned int u2 = gIn[(size_t)s2 * 64 + lane];
            unsigned int u3 = gIn[(size_t)s3 * 64 + lane];
            ax += bf_lo(u0); ay += bf_hi(u0);
            ax += bf_lo(u1); ay += bf_hi(u1);
            ax += bf_lo(u2); ay += bf_hi(u2);
            ax += bf_lo(u3); ay += bf_hi(u3);
        }
        for (; j < m; ++j) {
            int s0 = __shfl(cv, j);
            unsigned int u0 = gIn[(size_t)s0 * 64 + lane];
            ax += bf_lo(u0); ay += bf_hi(u0);
        }
        cv = cvn;
    }
    gOut[(size_t)i * 64 + lane] = pack_bf2(di * ax, di * ay);
}

// ---------------- MFMA matmul (layers 2,3): g_out = bf16(dinv * relu(A @ WT^T + b)) ---
// WTg: pre-transposed bf16 weights [n][k] (n-major). Staged to LDS stride 136.
// Output pre-scaled by dinv[node] for the next aggregation pass.

__global__ __launch_bounds__(256) void k_mmx(const unsigned int* __restrict__ gIn,
                                             const unsigned short* __restrict__ WTg,
                                             const float* __restrict__ bias,
                                             const float* __restrict__ dinv,
                                             unsigned int* __restrict__ outg) {
    __shared__ unsigned short sbuf[128 * 136];   // WT (stride 136), reused as Cs (stride 132)
    int t = threadIdx.x;
    // coalesced copy: 16384 shorts, 8 per thread per iter (uint4)
    for (int i = t * 8; i < 128 * 128; i += 256 * 8) {
        int n = i >> 7, k = i & 127;
        uint4 val = *(const uint4*)(WTg + i);
        *(uint4*)(sbuf + n * 136 + k) = val;
    }

    int lane = t & 63, wave = t >> 6;
    int m = lane & 15, quad = lane >> 4;
    int nodeBase = blockIdx.x * 128 + wave * 32;
    const short* gs = (const short*)gIn;

    float bi[8];
    #pragma unroll
    for (int nt = 0; nt < 8; ++nt) bi[nt] = bias[nt * 16 + m];

    f32x4 acc[2][8];
    #pragma unroll
    for (int gi = 0; gi < 2; ++gi)
        #pragma unroll
        for (int nt = 0; nt < 8; ++nt)
            acc[gi][nt] = (f32x4){0.f, 0.f, 0.f, 0.f};

    __syncthreads();

    #pragma unroll
    for (int kc = 0; kc < 4; ++kc) {
        bf16x8 ah[2];
        #pragma unroll
        for (int gi = 0; gi < 2; ++gi) {
            int node = nodeBase + gi * 16 + m;
            bf16x8 h = {0, 0, 0, 0, 0, 0, 0, 0};
            if (node < N_NODES)
                h = *(const bf16x8*)(gs + (size_t)node * 128 + kc * 32 + quad * 8);
            ah[gi] = h;
        }
        #pragma unroll
        for (int nt = 0; nt < 8; ++nt) {
            bf16x8 b = *(const bf16x8*)(sbuf + (nt * 16 + m) * 136 + kc * 32 + quad * 8);
            #pragma unroll
            for (int gi = 0; gi < 2; ++gi)
                acc[gi][nt] = __builtin_amdgcn_mfma_f32_16x16x32_bf16(ah[gi], b, acc[gi][nt], 0, 0, 0);
        }
    }

    __syncthreads();
    #pragma unroll
    for (int gi = 0; gi < 2; ++gi)
        #pragma unroll
        for (int r = 0; r < 4; ++r) {
            int nl = wave * 32 + gi * 16 + quad * 4 + r;
            int node = blockIdx.x * 128 + nl;
            float di = (node < N_NODES) ? dinv[node] : 0.f;
            #pragma unroll
            for (int nt = 0; nt < 8; ++nt) {
                float vv = acc[gi][nt][r] + bi[nt];
                sbuf[nl * 132 + nt * 16 + m] = (unsigned short)f2bf_rne(di * fmaxf(vv, 0.f));
            }
        }
    __syncthreads();
    for (int i = t; i < 128 * 32; i += 256) {
        int nl = i >> 5, p = i & 31;
        int node = blockIdx.x * 128 + nl;
        if (node < N_NODES) {
            uint2 val = *(const uint2*)(sbuf + nl * 132 + p * 4);
            *(uint2*)&outg[(size_t)node * 64 + p * 2] = val;
        }
    }
}

// ---------------- pool stage 1: per-chunk partial sums (bf16 in, fp32 atomics) -------

__global__ __launch_bounds__(256) void k_poolsum(const unsigned int* __restrict__ aggB,
                                                 const int* __restrict__ batch,
                                                 float* __restrict__ pooled) {
    int wid = (blockIdx.x * blockDim.x + threadIdx.x) >> 6;   // wave id: 16 nodes each
    int lane = threadIdx.x & 63;
    int n0 = wid * 16;
    if (n0 >= N_NODES) return;
    int n1 = n0 + 16; if (n1 > N_NODES) n1 = N_NODES;
    int curg = batch[n0];
    float ax = 0.f, ay = 0.f;
    for (int n = n0; n < n1; ++n) {
        int g = batch[n];
        if (g != curg) {
            atomicAdd(&pooled[curg * HID + 2 * lane], ax);
            atomicAdd(&pooled[curg * HID + 2 * lane + 1], ay);
            ax = 0.f; ay = 0.f; curg = g;
        }
        unsigned int u = aggB[(size_t)n * 64 + lane];
        ax += bf_lo(u); ay += bf_hi(u);
    }
    atomicAdd(&pooled[curg * HID + 2 * lane], ax);
    atomicAdd(&pooled[curg * HID + 2 * lane + 1], ay);
}

// ---------------- head: mean + fused W4*Wlin linear ----------------

__global__ void k_head(const float* __restrict__ pooled, const int* __restrict__ batch,
                       const float* __restrict__ Wc, const float* __restrict__ bc,
                       const float* __restrict__ blin, float* __restrict__ out) {
    int wid = (blockIdx.x * blockDim.x + threadIdx.x) >> 6;
    int lane = threadIdx.x & 63;
    if (wid >= NG) return;
    int g = wid;
    int lo = 0, hi = N_NODES;
    while (lo < hi) { int mid = (lo + hi) >> 1; if (batch[mid] < g) lo = mid + 1; else hi = mid; }
    int start = lo;
    hi = N_NODES;
    while (lo < hi) { int mid = (lo + hi) >> 1; if (batch[mid] < g + 1) lo = mid + 1; else hi = mid; }
    int cnt = lo - start;
    float invc = (cnt > 0) ? 1.0f / (float)cnt : 0.f;
    float px = pooled[g * HID + 2 * lane] * invc;
    float py = pooled[g * HID + 2 * lane + 1] * invc;

    #pragma unroll
    for (int o = 0; o < 2; ++o) {
        float v = px * Wc[(2 * lane) * 2 + o] + py * Wc[(2 * lane + 1) * 2 + o];
        #pragma unroll
        for (int s = 32; s > 0; s >>= 1) v += __shfl_down(v, s);
        if (lane == 0) out[g * 2 + o] = (cnt > 0) ? (v + bc[o]) : blin[o];
    }
}

// ---------------- launcher ----------------

extern "C" void kernel_launch(void* const* d_in, const int* in_sizes, int n_in,
                              void* d_out, int out_size, void* d_ws, size_t ws_size,
                              hipStream_t stream) {
    const float* x    = (const float*)d_in[0];
    const int*   eidx = (const int*)d_in[1];
    const int*   batch= (const int*)d_in[2];
    const float* W1   = (const float*)d_in[3];
    const float* b1   = (const float*)d_in[4];
    const float* W2   = (const float*)d_in[5];
    const float* b2   = (const float*)d_in[6];
    const float* W3   = (const float*)d_in[7];
    const float* b3   = (const float*)d_in[8];
    const float* W4   = (const float*)d_in[9];
    const float* b4   = (const float*)d_in[10];
    const float* Wlin = (const float*)d_in[11];
    const float* blin = (const float*)d_in[12];
    float* out = (float*)d_out;

    // workspace carve-up (256B aligned)
    char* ws = (char*)d_ws;
    size_t off = 0;
    auto carve = [&](size_t bytes) { char* p = ws + off; off = (off + bytes + 255) & ~(size_t)255; return p; };
    int*   rowptr    = (int*)carve((size_t)(N_NODES + 1) * 4);
    float* dinv      = (float*)carve((size_t)N_NODES * 4);
    int*   col       = (int*)carve((size_t)E_EDGES * 4);    // k_aggW over-reads <=63 ints into ebuf: safe
    unsigned int* ebuf = (unsigned int*)carve((size_t)E_EDGES * 4);
    int*   table     = (int*)carve((size_t)TLEN * 4);
    int*   partial   = (int*)carve((size_t)NCH * 4);
    int*   bucketBase= (int*)carve((size_t)(NBUCK + 1) * 4);
    unsigned int* gA = (unsigned int*)carve((size_t)N_NODES * 64 * 4);   // 25.6 MB bf16 buffer
    unsigned int* gB = (unsigned int*)carve((size_t)N_NODES * 64 * 4);   // 25.6 MB bf16 buffer
    float* pooled    = (float*)carve((size_t)NG * HID * 4);
    float* Wc        = (float*)carve((size_t)HID * 2 * 4);
    float* bc        = (float*)carve(2 * 4);
    unsigned short* WT2 = (unsigned short*)carve((size_t)HID * HID * 2);
    unsigned short* WT3 = (unsigned short*)carve((size_t)HID * HID * 2);
    (void)ws_size; (void)n_in; (void)in_sizes; (void)out_size;

    const int BLK = 256;
    int gridL1 = (N_NODES + 31) / 32;               // 3125
    int gridPS = ((N_NODES + 15) / 16 * 64 + BLK - 1) / BLK;
    int gridHead = (NG * 64 + BLK - 1) / BLK;

    // CSR hist + pooled zero + Wc fold + WT2/WT3 conversion (single fused dispatch)
    k_hist2<<<NBLK_SC + 193, BLK, 0, stream>>>(eidx, table, W4, b4, Wlin, blin,
                                               Wc, bc, pooled, W2, W3, WT2, WT3);
    k_blocksum<<<NCH, BLK, 0, stream>>>(table, partial);
    k_scan_blk<<<1, 256, 0, stream>>>(partial, bucketBase, rowptr);
    k_scan_final<<<NCH, 1024, 0, stream>>>(table, partial, bucketBase);
    k_scatter2<<<NBLK_SC, BLK, 0, stream>>>(eidx, table, ebuf);
    k_bucket<<<NBUCK, BLK, 0, stream>>>(ebuf, bucketBase, rowptr, dinv, col);

    // layer 1 (fused agg + matmul), output pre-scaled by dinv
    k_l1<<<gridL1, BLK, 0, stream>>>(x, W1, b1, rowptr, col, dinv, gA);

    // layer 2: a2 = A' g1 -> MFMA mm (pre-scaled out) -> g2
    k_aggW<<<AGGW_GRID, BLK, 0, stream>>>(gA, gB, rowptr, col, dinv);
    k_mmx<<<MMX_GRID, BLK, 0, stream>>>(gB, WT2, b2, dinv, gA);
    // layer 3: a3 = A' g2 -> MFMA mm (pre-scaled out) -> g3
    k_aggW<<<AGGW_GRID, BLK, 0, stream>>>(gA, gB, rowptr, col, dinv);
    k_mmx<<<MMX_GRID, BLK, 0, stream>>>(gB, WT3, b3, dinv, gA);
    // layer 4: aggregation only (W4 folded into head), true aggregate out
    k_aggW<<<AGGW_GRID, BLK, 0, stream>>>(gA, gB, rowptr, col, dinv);

    // pool + head
    k_poolsum<<<gridPS, BLK, 0, stream>>>(gB, batch, pooled);
    k_head<<<gridHead, BLK, 0, stream>>>(pooled, batch, Wc, bc, blin, out);
}